// Round 3
// baseline (662.157 us; speedup 1.0000x reference)
//
#include <hip/hip_runtime.h>
#include <hip/hip_bf16.h>
#include <stdint.h>

typedef __attribute__((ext_vector_type(8))) __bf16 bf16x8;
typedef __attribute__((ext_vector_type(8))) unsigned short ushort8;
typedef __attribute__((ext_vector_type(4))) float f32x4;
typedef __attribute__((ext_vector_type(4))) unsigned int u32x4;

#define N_NODES 100000
#define N_EDGES 800000
#define FIN 128
#define FH 512
#define FO 40
#define NCHUNK 391   // ceil(N/256)
#define TWBLKS 352   // (128*512 + 48*512)/256

// workspace byte offsets (16B-aligned where vector loads occur)
#define O_DINV   0ull            // N floats
#define O_CNT    400000ull       // N ints
#define O_ROWPTR 800000ull       // N+1 ints
#define O_CUR    1200016ull      // N ints
#define O_SRC    1600016ull      // E ints   (src sorted by dst)
#define O_DSRC   4800016ull      // E floats (dinv[src] sorted by dst)
#define O_W1T    8000016ull      // 512x128 bf16
#define O_W2T    8131088ull      // 48x512 bf16 (zero-padded cols 40..47)
#define O_AXG    8180240ull      // N x 128 f32  (aggregated x)
#define O_H2     59380240ull     // N x 40 f32; ALSO aliased as mask8 (6.4 MB)
                                 // lifetimes: mask8 written k_aggx, read k_gemm1f;
                                 // h2 written k_gemm2 (after), read k_agg2. No overlap.
#define O_PART   75380240ull     // 512 ints

__device__ __forceinline__ unsigned short f2bf(float f) {
  unsigned u = __float_as_uint(f);
  u += 0x7fffu + ((u >> 16) & 1u);           // round-to-nearest-even
  return (unsigned short)(u >> 16);
}

// truncating f32x8 -> bf16x8 pack from registers (staging for MFMA A)
__device__ __forceinline__ bf16x8 pack8t(u32x4 a, u32x4 b) {
  u32x4 w;
  w.x = __builtin_amdgcn_perm(a.y, a.x, 0x07060302u);
  w.y = __builtin_amdgcn_perm(a.w, a.z, 0x07060302u);
  w.z = __builtin_amdgcn_perm(b.y, b.x, 0x07060302u);
  w.w = __builtin_amdgcn_perm(b.w, b.z, 0x07060302u);
  return __builtin_bit_cast(bf16x8, w);
}

// ---------------- degree count ----------------

__global__ __launch_bounds__(256) void k_count(const int* __restrict__ dst,
                                               int* __restrict__ cnt) {
  int e = blockIdx.x * 256 + threadIdx.x;
  if (e < N_EDGES) atomicAdd(&cnt[__builtin_nontemporal_load(&dst[e])], 1);
}

// ---------------- scan chunk-local + dinv + weight transposes, fused ----------------

__global__ __launch_bounds__(256) void k_scan1tw(const int* __restrict__ cnt,
                                                 int* __restrict__ rowptr,
                                                 int* __restrict__ partials,
                                                 float* __restrict__ dinv,
                                                 const float* __restrict__ w1,
                                                 const float* __restrict__ w2,
                                                 unsigned short* __restrict__ w1t,
                                                 unsigned short* __restrict__ w2t) {
  int b = blockIdx.x;
  if (b >= NCHUNK) {                         // weight-transpose blocks
    int t = (b - NCHUNK) * 256 + threadIdx.x;
    if (t < FIN * FH) {                      // W1^T: [512c][128k]
      int c = t >> 7, k = t & 127;
      w1t[c * 128 + k] = f2bf(w1[k * FH + c]);
    } else {                                 // W2^T: [48c][512k], pad c>=40
      int u = t - FIN * FH;
      int c = u >> 9, k = u & 511;
      w2t[c * FH + k] = (c < FO) ? f2bf(w2[k * FO + c]) : (unsigned short)0;
    }
    return;
  }
  int t = threadIdx.x, g = b * 256 + t;
  int v = (g < N_NODES) ? cnt[g] : 0;
  if (g < N_NODES) dinv[g] = __frsqrt_rn((float)(v + 1));
  int lane = t & 63, w = t >> 6;
  int sc = v;
#pragma unroll
  for (int off = 1; off < 64; off <<= 1) {
    int u = __shfl_up(sc, off);
    if (lane >= off) sc += u;
  }
  __shared__ int wsum[4];
  if (lane == 63) wsum[w] = sc;
  __syncthreads();
  int add = 0;
  for (int j = 0; j < w; j++) add += wsum[j];
  int incl = sc + add;
  if (g < N_NODES) rowptr[g] = incl - v;     // chunk-local exclusive
  if (t == 255) partials[b] = incl;
}

// ---------------- global scan offsets + cur init ----------------

__global__ __launch_bounds__(256) void k_scan3(int* __restrict__ rowptr,
                                               const int* __restrict__ partials,
                                               int* __restrict__ cur) {
  __shared__ int sbase;
  int t = threadIdx.x;
  int chunk = blockIdx.x;
  if (t < 64) {                              // wave 0: base = sum partials[0..chunk)
    int s = 0;
    for (int j = t; j < chunk; j += 64) s += partials[j];
#pragma unroll
    for (int off = 32; off; off >>= 1) s += __shfl_down(s, off);
    if (t == 0) sbase = s;
  }
  __syncthreads();
  int base = sbase;
  int g = chunk * 256 + t;
  if (g < N_NODES) {
    int v = rowptr[g] + base;
    rowptr[g] = v;
    cur[g] = v;
  } else if (g == N_NODES) {
    rowptr[N_NODES] = N_EDGES;
  }
}

__global__ __launch_bounds__(256) void k_scatter(const int* __restrict__ src,
                                                 const int* __restrict__ dst,
                                                 const float* __restrict__ dinv,
                                                 int* __restrict__ cur,
                                                 int* __restrict__ src_sorted,
                                                 float* __restrict__ dinv_src) {
  int e = blockIdx.x * 256 + threadIdx.x;
  if (e < N_EDGES) {
    int s = __builtin_nontemporal_load(&src[e]);
    int d = __builtin_nontemporal_load(&dst[e]);
    int pos = atomicAdd(&cur[d], 1);
    src_sorted[pos] = s;
    dinv_src[pos] = dinv[s];
  }
}

// ---------------- dropout bits (JAX partitionable threefry, key=42) ----------------

__device__ __forceinline__ unsigned tf_bits(unsigned x0, unsigned x1) {
  const unsigned K0 = 0u, K1 = 42u, K2 = 0x1BD11BDAu ^ 42u;
  x0 += K0; x1 += K1;
#define RND(r) { x0 += x1; x1 = (x1 << (r)) | (x1 >> (32 - (r))); x1 ^= x0; }
  RND(13) RND(15) RND(26) RND(6)
  x0 += K1; x1 += K2 + 1u;
  RND(17) RND(29) RND(16) RND(24)
  x0 += K2; x1 += K0 + 2u;
  RND(13) RND(15) RND(26) RND(6)
  x0 += K0; x1 += K1 + 3u;
  RND(17) RND(29) RND(16) RND(24)
  x0 += K1; x1 += K2 + 4u;
  RND(13) RND(15) RND(26) RND(6)
  x0 += K2; x1 += K0 + 5u;
#undef RND
  return x0 ^ x1;   // partitionable path xor-folds (out0, out1)
}

// ---------------- aggregate x + dropout-mask generation, fused ----------------
// axg = D^-1/2 (A+I) D^-1/2 x  (commuted vs reference: (A(XW1)) == (AX)W1).
// One wave per node. The wave ALSO generates node i's 512 dropout-mask bits
// (8 threefry hashes/lane, packed 1 bit/elem -> 64 B/node): this kernel is
// gather-latency-bound with an idle VALU, so the ~50 us of threefry work
// hides under the memory stalls instead of competing with gemm1f's stores.
// Mask layout: byte row*64 + (col>>3), bit (col&7).

__global__ __launch_bounds__(256) void k_aggx(const float* __restrict__ x,
                                              const int* __restrict__ rowptr,
                                              const int* __restrict__ src_sorted,
                                              const float* __restrict__ dinv_src,
                                              const float* __restrict__ dinv,
                                              float* __restrict__ axg,
                                              unsigned char* __restrict__ mask8) {
  int i = blockIdx.x * 4 + (threadIdx.x >> 6);
  int lane = threadIdx.x & 63;
  int rs = rowptr[i], re = rowptr[i + 1];
  float di = dinv[i];
  int c = lane << 1;                         // 2 channels per lane

  // dropout mask for row i (independent of everything -> fills stall slots)
  {
    unsigned fb = (unsigned)i * FH + ((unsigned)lane << 3);
    unsigned mb = 0;
#pragma unroll
    for (int q = 0; q < 8; q++)
      mb |= ((~tf_bits(0u, fb + q)) >> 31) << q;   // keep iff top bit == 0
    mask8[((size_t)i << 6) | lane] = (unsigned char)mb;
  }

  float a0 = 0.0f, a1 = 0.0f;

  for (int base = rs; base < re; base += 64) {
    int n = re - base; if (n > 64) n = 64;
    int myi = 0; float myw = 0.0f;
    if (lane < n) {
      myi = src_sorted[base + lane];
      myw = dinv_src[base + lane];
    }
    int j = 0;
    for (; j + 4 <= n; j += 4) {             // 4 gathers in flight
      int s0 = __shfl(myi, j),     s1 = __shfl(myi, j + 1);
      int s2 = __shfl(myi, j + 2), s3 = __shfl(myi, j + 3);
      float w0 = __shfl(myw, j),      w1_ = __shfl(myw, j + 1);
      float w2_ = __shfl(myw, j + 2), w3_ = __shfl(myw, j + 3);
      float2 v0 = *(const float2*)(x + (((size_t)s0 << 7) | c));
      float2 v1 = *(const float2*)(x + (((size_t)s1 << 7) | c));
      float2 v2 = *(const float2*)(x + (((size_t)s2 << 7) | c));
      float2 v3 = *(const float2*)(x + (((size_t)s3 << 7) | c));
      a0 += w0 * v0.x + w1_ * v1.x + w2_ * v2.x + w3_ * v3.x;
      a1 += w0 * v0.y + w1_ * v1.y + w2_ * v2.y + w3_ * v3.y;
    }
    for (; j < n; j++) {
      int s0 = __shfl(myi, j);
      float w0 = __shfl(myw, j);
      float2 v0 = *(const float2*)(x + (((size_t)s0 << 7) | c));
      a0 += w0 * v0.x; a1 += w0 * v0.y;
    }
  }
  { // self loop, weight di
    float2 vs = *(const float2*)(x + (((size_t)i << 7) | c));
    a0 += di * vs.x; a1 += di * vs.y;
  }
  float2 o; o.x = a0 * di; o.y = a1 * di;
  *(float2*)(axg + (((size_t)i << 7) | c)) = o;
}

// ---------------- GEMM1 fused: hidden = dropout(relu(axg @ W1 + b1)) ----------------
// 16x16x32 bf16 MFMA. A: A[m=lane&15][k=(lane>>4)*8+j]. C/D: col=lane&15, row=(lane>>4)*4+reg.
// Original 32rows x 512cols/block tiling (measured faster than the split-col
// variant: FETCH stays ~28 MB). Dropout now applied from the precomputed packed
// mask (8x 16B loads + shift/and per element) instead of 64 threefry hashes per
// thread -> VALU work drops ~10x; kernel should be bound by the 205 MB store.
// Bit extraction: word t>>1, bit (t&1)*16 + m  (derived from mask layout).

__global__ __launch_bounds__(256) void k_gemm1f(const float* __restrict__ axg,
                                                const unsigned short* __restrict__ w1t,
                                                const float* __restrict__ b1,
                                                const unsigned char* __restrict__ mask8,
                                                float* __restrict__ hidden) {
  int w = threadIdx.x >> 6;
  int lane = threadIdx.x & 63;
  int m = lane & 15, kg = lane >> 4;
  int r0 = blockIdx.x * 32;                  // 32 rows per block
  int cw = w * 128;                          // 128 cols per wave
  f32x4 acc[2][8];
#pragma unroll
  for (int a = 0; a < 2; a++)
#pragma unroll
    for (int t = 0; t < 8; t++)
#pragma unroll
      for (int r = 0; r < 4; r++) acc[a][t][r] = 0.0f;

  const float* xa0 = axg + (size_t)(r0 + m) * FIN + kg * 8;
  const float* xa1 = xa0 + 16 * FIN;
#pragma unroll
  for (int kc = 0; kc < 4; kc++) {
    int kb = kc * 32;
    u32x4 a0l = *(const u32x4*)(xa0 + kb);
    u32x4 a0h = *(const u32x4*)(xa0 + kb + 4);
    u32x4 a1l = *(const u32x4*)(xa1 + kb);
    u32x4 a1h = *(const u32x4*)(xa1 + kb + 4);
    bf16x8 a0 = pack8t(a0l, a0h);
    bf16x8 a1 = pack8t(a1l, a1h);
#pragma unroll
    for (int t = 0; t < 8; t++) {
      const unsigned short* bp = w1t + (size_t)(cw + t * 16 + m) * FIN + kb + kg * 8;
      bf16x8 b = __builtin_bit_cast(bf16x8, *(const ushort8*)bp);
      acc[0][t] = __builtin_amdgcn_mfma_f32_16x16x32_bf16(a0, b, acc[0][t], 0, 0, 0);
      acc[1][t] = __builtin_amdgcn_mfma_f32_16x16x32_bf16(a1, b, acc[1][t], 0, 0, 0);
    }
  }

  float bcol[8];
#pragma unroll
  for (int t = 0; t < 8; t++) bcol[t] = b1[cw + t * 16 + m];

  // per-row 16B mask segment covering this wave's 128 cols
  u32x4 mv[2][4];
#pragma unroll
  for (int rt = 0; rt < 2; rt++)
#pragma unroll
    for (int r = 0; r < 4; r++) {
      int row = r0 + rt * 16 + kg * 4 + r;
      mv[rt][r] = *(const u32x4*)(mask8 + (size_t)row * 64 + w * 16);
    }

#pragma unroll
  for (int rt = 0; rt < 2; rt++)
#pragma unroll
    for (int t = 0; t < 8; t++)
#pragma unroll
      for (int r = 0; r < 4; r++) {
        int row = r0 + rt * 16 + kg * 4 + r;
        int col = cw + t * 16 + m;
        unsigned flat = (unsigned)row * FH + (unsigned)col;
        float v = fmaxf(acc[rt][t][r] + bcol[t], 0.0f);
        unsigned keep = (mv[rt][r][t >> 1] >> ((t & 1) * 16 + m)) & 1u;
        hidden[flat] = keep ? v * 2.0f : 0.0f;
      }
}

// ---------------- GEMM2: h2[N,40] = hidden[N,512] @ W2 (bf16 MFMA, cols padded 48) ----------------

__global__ __launch_bounds__(256) void k_gemm2(const float* __restrict__ hidden,
                                               const unsigned short* __restrict__ w2t,
                                               float* __restrict__ h2) {
  int wid = blockIdx.x * 4 + (threadIdx.x >> 6);
  if (wid >= N_NODES / 16) return;
  int lane = threadIdx.x & 63;
  int m = lane & 15, kg = lane >> 4;
  int r0 = wid * 16;
  f32x4 acc[3];
#pragma unroll
  for (int t = 0; t < 3; t++)
#pragma unroll
    for (int r = 0; r < 4; r++) acc[t][r] = 0.0f;

  const float* ap = hidden + (size_t)(r0 + m) * FH + kg * 8;
#pragma unroll 8
  for (int kc = 0; kc < 16; kc++) {
    int kb = kc * 32;
    u32x4 al = __builtin_nontemporal_load((const u32x4*)(ap + kb));
    u32x4 ah = __builtin_nontemporal_load((const u32x4*)(ap + kb + 4));
    bf16x8 a = pack8t(al, ah);
#pragma unroll
    for (int t = 0; t < 3; t++) {
      bf16x8 b = __builtin_bit_cast(bf16x8,
          *(const ushort8*)(w2t + (size_t)(t * 16 + m) * FH + kb + kg * 8));
      acc[t] = __builtin_amdgcn_mfma_f32_16x16x32_bf16(a, b, acc[t], 0, 0, 0);
    }
  }
#pragma unroll
  for (int t = 0; t < 3; t++)
#pragma unroll
    for (int r = 0; r < 4; r++) {
      int row = r0 + kg * 4 + r;
      int col = t * 16 + m;
      if (col < FO) h2[(size_t)row * FO + col] = acc[t][r];
    }
}

// ---------------- aggregate L2 + bias -> out (f32); h2 = 16 MB, LLC-resident ----------------

__global__ __launch_bounds__(256) void k_agg2(const float* __restrict__ h2,
                                              const int* __restrict__ rowptr,
                                              const int* __restrict__ src_sorted,
                                              const float* __restrict__ dinv_src,
                                              const float* __restrict__ dinv,
                                              const float* __restrict__ b2,
                                              float* __restrict__ out) {
  int i = blockIdx.x * 4 + (threadIdx.x >> 6);
  int lane = threadIdx.x & 63;
  int rs = rowptr[i], re = rowptr[i + 1];
  float di = dinv[i];
  float acc = 0.0f;

  for (int base = rs; base < re; base += 64) {
    int n = re - base; if (n > 64) n = 64;
    int myi = 0; float myw = 0.0f;
    if (lane < n) {
      myi = __builtin_nontemporal_load(&src_sorted[base + lane]);
      myw = __builtin_nontemporal_load(&dinv_src[base + lane]);
    }
    for (int j = 0; j < n; j++) {
      int s = __shfl(myi, j);
      float wgt = __shfl(myw, j);
      if (lane < FO) acc += wgt * h2[(size_t)s * FO + lane];
    }
  }
  if (lane < FO) {
    acc += di * h2[(size_t)i * FO + lane];
    out[(size_t)i * FO + lane] = acc * di + b2[lane];
  }
}

// ---------------- launcher ----------------

extern "C" void kernel_launch(void* const* d_in, const int* in_sizes, int n_in,
                              void* d_out, int out_size, void* d_ws, size_t ws_size,
                              hipStream_t stream) {
  const float* x  = (const float*)d_in[0];
  const int* ei   = (const int*)d_in[1];
  const float* w1 = (const float*)d_in[2];
  const float* b1 = (const float*)d_in[3];
  const float* w2 = (const float*)d_in[4];
  const float* b2 = (const float*)d_in[5];

  char* ws = (char*)d_ws;
  float* dinv            = (float*)(ws + O_DINV);
  int* cnt               = (int*)(ws + O_CNT);
  int* rowptr            = (int*)(ws + O_ROWPTR);
  int* cur               = (int*)(ws + O_CUR);
  int* src_sorted        = (int*)(ws + O_SRC);
  float* dinv_src        = (float*)(ws + O_DSRC);
  unsigned short* w1t    = (unsigned short*)(ws + O_W1T);
  unsigned short* w2t    = (unsigned short*)(ws + O_W2T);
  float* axg             = (float*)(ws + O_AXG);
  float* h2              = (float*)(ws + O_H2);
  unsigned char* mask8   = (unsigned char*)(ws + O_H2);   // aliased: dead before h2 lives
  int* partials          = (int*)(ws + O_PART);

  float* outp   = (float*)d_out;                       // [N,40]
  float* hidden = outp + (size_t)N_NODES * FO;         // [N,512]

  const int* srcA = ei;             // edge_index[0]
  const int* dstA = ei + N_EDGES;   // edge_index[1]

  hipMemsetAsync(cnt, 0, N_NODES * sizeof(int), stream);
  k_count<<<(N_EDGES + 255) / 256, 256, 0, stream>>>(dstA, cnt);
  k_scan1tw<<<NCHUNK + TWBLKS, 256, 0, stream>>>(cnt, rowptr, partials, dinv,
                                                 w1, w2, w1t, w2t);
  k_scan3<<<NCHUNK, 256, 0, stream>>>(rowptr, partials, cur);
  k_scatter<<<(N_EDGES + 255) / 256, 256, 0, stream>>>(srcA, dstA, dinv, cur,
                                                       src_sorted, dinv_src);
  k_aggx<<<N_NODES / 4, 256, 0, stream>>>(x, rowptr, src_sorted, dinv_src, dinv,
                                          axg, mask8);
  k_gemm1f<<<N_NODES / 32, 256, 0, stream>>>(axg, w1t, b1, mask8, hidden);
  k_gemm2<<<(N_NODES / 16 + 3) / 4, 256, 0, stream>>>(hidden, w2t, h2);
  k_agg2<<<N_NODES / 4, 256, 0, stream>>>(h2, rowptr, src_sorted, dinv_src, dinv,
                                          b2, outp);
}

// Round 4
// 623.370 us; speedup vs baseline: 1.0622x; 1.0622x over previous
//
#include <hip/hip_runtime.h>
#include <hip/hip_bf16.h>
#include <stdint.h>

typedef __attribute__((ext_vector_type(8))) __bf16 bf16x8;
typedef __attribute__((ext_vector_type(8))) unsigned short ushort8;
typedef __attribute__((ext_vector_type(4))) float f32x4;
typedef __attribute__((ext_vector_type(4))) unsigned int u32x4;

#define N_NODES 100000
#define N_EDGES 800000
#define FIN 128
#define FH 512
#define FO 40
#define NCHUNK 391   // ceil(N/256)
#define TWBLKS 352   // (128*512 + 48*512)/256

// workspace byte offsets (16B-aligned where vector loads occur)
#define O_DINV   0ull            // N floats
#define O_CNT    400000ull       // N ints
#define O_ROWPTR 800000ull       // N+1 ints
#define O_CUR    1200016ull      // N ints
#define O_SRC    1600016ull      // E ints   (src sorted by dst)
#define O_DSRC   4800016ull      // E floats (dinv[src] sorted by dst)
#define O_W1T    8000016ull      // 512x128 bf16
#define O_W2T    8131088ull      // 48x512 bf16 (zero-padded cols 40..47)
#define O_AXG    8180240ull      // N x 128 f32  (aggregated x)
#define O_H2     59380240ull     // N x 40 f32 (written by fused gemm, read by agg2)
#define O_PART   75380240ull     // 512 ints
#define O_MASK   75400000ull     // N x 64 B packed dropout mask (6.4 MB)
                                 // NOTE: no longer aliased with h2 -- with gemm2 fused,
                                 // h2 writes and mask reads overlap in time across blocks.

__device__ __forceinline__ unsigned short f2bf(float f) {
  unsigned u = __float_as_uint(f);
  u += 0x7fffu + ((u >> 16) & 1u);           // round-to-nearest-even
  return (unsigned short)(u >> 16);
}

// truncating f32x8 -> bf16x8 pack from registers (staging for MFMA A)
__device__ __forceinline__ bf16x8 pack8t(u32x4 a, u32x4 b) {
  u32x4 w;
  w.x = __builtin_amdgcn_perm(a.y, a.x, 0x07060302u);
  w.y = __builtin_amdgcn_perm(a.w, a.z, 0x07060302u);
  w.z = __builtin_amdgcn_perm(b.y, b.x, 0x07060302u);
  w.w = __builtin_amdgcn_perm(b.w, b.z, 0x07060302u);
  return __builtin_bit_cast(bf16x8, w);
}

// ---------------- degree count ----------------

__global__ __launch_bounds__(256) void k_count(const int* __restrict__ dst,
                                               int* __restrict__ cnt) {
  int e = blockIdx.x * 256 + threadIdx.x;
  if (e < N_EDGES) atomicAdd(&cnt[__builtin_nontemporal_load(&dst[e])], 1);
}

// ---------------- scan chunk-local + dinv + weight transposes, fused ----------------

__global__ __launch_bounds__(256) void k_scan1tw(const int* __restrict__ cnt,
                                                 int* __restrict__ rowptr,
                                                 int* __restrict__ partials,
                                                 float* __restrict__ dinv,
                                                 const float* __restrict__ w1,
                                                 const float* __restrict__ w2,
                                                 unsigned short* __restrict__ w1t,
                                                 unsigned short* __restrict__ w2t) {
  int b = blockIdx.x;
  if (b >= NCHUNK) {                         // weight-transpose blocks
    int t = (b - NCHUNK) * 256 + threadIdx.x;
    if (t < FIN * FH) {                      // W1^T: [512c][128k]
      int c = t >> 7, k = t & 127;
      w1t[c * 128 + k] = f2bf(w1[k * FH + c]);
    } else {                                 // W2^T: [48c][512k], pad c>=40
      int u = t - FIN * FH;
      int c = u >> 9, k = u & 511;
      w2t[c * FH + k] = (c < FO) ? f2bf(w2[k * FO + c]) : (unsigned short)0;
    }
    return;
  }
  int t = threadIdx.x, g = b * 256 + t;
  int v = (g < N_NODES) ? cnt[g] : 0;
  if (g < N_NODES) dinv[g] = __frsqrt_rn((float)(v + 1));
  int lane = t & 63, w = t >> 6;
  int sc = v;
#pragma unroll
  for (int off = 1; off < 64; off <<= 1) {
    int u = __shfl_up(sc, off);
    if (lane >= off) sc += u;
  }
  __shared__ int wsum[4];
  if (lane == 63) wsum[w] = sc;
  __syncthreads();
  int add = 0;
  for (int j = 0; j < w; j++) add += wsum[j];
  int incl = sc + add;
  if (g < N_NODES) rowptr[g] = incl - v;     // chunk-local exclusive
  if (t == 255) partials[b] = incl;
}

// ---------------- global scan offsets + cur init ----------------

__global__ __launch_bounds__(256) void k_scan3(int* __restrict__ rowptr,
                                               const int* __restrict__ partials,
                                               int* __restrict__ cur) {
  __shared__ int sbase;
  int t = threadIdx.x;
  int chunk = blockIdx.x;
  if (t < 64) {                              // wave 0: base = sum partials[0..chunk)
    int s = 0;
    for (int j = t; j < chunk; j += 64) s += partials[j];
#pragma unroll
    for (int off = 32; off; off >>= 1) s += __shfl_down(s, off);
    if (t == 0) sbase = s;
  }
  __syncthreads();
  int base = sbase;
  int g = chunk * 256 + t;
  if (g < N_NODES) {
    int v = rowptr[g] + base;
    rowptr[g] = v;
    cur[g] = v;
  } else if (g == N_NODES) {
    rowptr[N_NODES] = N_EDGES;
  }
}

__global__ __launch_bounds__(256) void k_scatter(const int* __restrict__ src,
                                                 const int* __restrict__ dst,
                                                 const float* __restrict__ dinv,
                                                 int* __restrict__ cur,
                                                 int* __restrict__ src_sorted,
                                                 float* __restrict__ dinv_src) {
  int e = blockIdx.x * 256 + threadIdx.x;
  if (e < N_EDGES) {
    int s = __builtin_nontemporal_load(&src[e]);
    int d = __builtin_nontemporal_load(&dst[e]);
    int pos = atomicAdd(&cur[d], 1);
    src_sorted[pos] = s;
    dinv_src[pos] = dinv[s];
  }
}

// ---------------- dropout bits (JAX partitionable threefry, key=42) ----------------

__device__ __forceinline__ unsigned tf_bits(unsigned x0, unsigned x1) {
  const unsigned K0 = 0u, K1 = 42u, K2 = 0x1BD11BDAu ^ 42u;
  x0 += K0; x1 += K1;
#define RND(r) { x0 += x1; x1 = (x1 << (r)) | (x1 >> (32 - (r))); x1 ^= x0; }
  RND(13) RND(15) RND(26) RND(6)
  x0 += K1; x1 += K2 + 1u;
  RND(17) RND(29) RND(16) RND(24)
  x0 += K2; x1 += K0 + 2u;
  RND(13) RND(15) RND(26) RND(6)
  x0 += K0; x1 += K1 + 3u;
  RND(17) RND(29) RND(16) RND(24)
  x0 += K1; x1 += K2 + 4u;
  RND(13) RND(15) RND(26) RND(6)
  x0 += K2; x1 += K0 + 5u;
#undef RND
  return x0 ^ x1;   // partitionable path xor-folds (out0, out1)
}

// ---------------- aggregate x + dropout-mask generation, fused ----------------
// axg = D^-1/2 (A+I) D^-1/2 x  (commuted vs reference: (A(XW1)) == (AX)W1).
// One wave per node; the wave also generates node i's 512 packed mask bits.
// Mask layout: byte row*64 + (col>>3), bit (col&7).

__global__ __launch_bounds__(256) void k_aggx(const float* __restrict__ x,
                                              const int* __restrict__ rowptr,
                                              const int* __restrict__ src_sorted,
                                              const float* __restrict__ dinv_src,
                                              const float* __restrict__ dinv,
                                              float* __restrict__ axg,
                                              unsigned char* __restrict__ mask8) {
  int i = blockIdx.x * 4 + (threadIdx.x >> 6);
  int lane = threadIdx.x & 63;
  int rs = rowptr[i], re = rowptr[i + 1];
  float di = dinv[i];
  int c = lane << 1;                         // 2 channels per lane

  // dropout mask for row i (independent -> fills gather-stall slots)
  {
    unsigned fb = (unsigned)i * FH + ((unsigned)lane << 3);
    unsigned mb = 0;
#pragma unroll
    for (int q = 0; q < 8; q++)
      mb |= ((~tf_bits(0u, fb + q)) >> 31) << q;   // keep iff top bit == 0
    mask8[((size_t)i << 6) | lane] = (unsigned char)mb;
  }

  float a0 = 0.0f, a1 = 0.0f;

  for (int base = rs; base < re; base += 64) {
    int n = re - base; if (n > 64) n = 64;
    int myi = 0; float myw = 0.0f;
    if (lane < n) {
      myi = src_sorted[base + lane];
      myw = dinv_src[base + lane];
    }
    int j = 0;
    for (; j + 4 <= n; j += 4) {             // 4 gathers in flight
      int s0 = __shfl(myi, j),     s1 = __shfl(myi, j + 1);
      int s2 = __shfl(myi, j + 2), s3 = __shfl(myi, j + 3);
      float w0 = __shfl(myw, j),      w1_ = __shfl(myw, j + 1);
      float w2_ = __shfl(myw, j + 2), w3_ = __shfl(myw, j + 3);
      float2 v0 = *(const float2*)(x + (((size_t)s0 << 7) | c));
      float2 v1 = *(const float2*)(x + (((size_t)s1 << 7) | c));
      float2 v2 = *(const float2*)(x + (((size_t)s2 << 7) | c));
      float2 v3 = *(const float2*)(x + (((size_t)s3 << 7) | c));
      a0 += w0 * v0.x + w1_ * v1.x + w2_ * v2.x + w3_ * v3.x;
      a1 += w0 * v0.y + w1_ * v1.y + w2_ * v2.y + w3_ * v3.y;
    }
    for (; j < n; j++) {
      int s0 = __shfl(myi, j);
      float w0 = __shfl(myw, j);
      float2 v0 = *(const float2*)(x + (((size_t)s0 << 7) | c));
      a0 += w0 * v0.x; a1 += w0 * v0.y;
    }
  }
  { // self loop, weight di
    float2 vs = *(const float2*)(x + (((size_t)i << 7) | c));
    a0 += di * vs.x; a1 += di * vs.y;
  }
  float2 o; o.x = a0 * di; o.y = a1 * di;
  *(float2*)(axg + (((size_t)i << 7) | c)) = o;
}

// ---------------- FUSED GEMM1+GEMM2 ----------------
// Phase 1: hidden = dropout(relu(axg @ W1 + b1))  [32 rows x 512 cols per block]
//   - stores f32 hidden to global (mandatory output)
//   - stages truncated-bf16 hidden into a 32 KB LDS tile (bit-identical to the
//     old pack8t path), XOR-swizzled byte ^= (row&15)<<4 so phase-2
//     ds_read_b128 spreads 4 lanes per 16B slot -> conflict-free.
// Phase 2: each wave contracts its own K=128 slice vs W2^T -> 32x48 partial.
// Phase 3: cross-wave reduce in (reused) LDS, write h2[32][40].
// This deletes k_gemm2 and its full 205 MB re-read of hidden.

__global__ __launch_bounds__(256) void k_gemm12(const float* __restrict__ axg,
                                                const unsigned short* __restrict__ w1t,
                                                const float* __restrict__ b1,
                                                const unsigned char* __restrict__ mask8,
                                                const unsigned short* __restrict__ w2t,
                                                float* __restrict__ hidden,
                                                float* __restrict__ h2) {
  __shared__ __align__(16) char smem[32768];   // bf16 tile [32][512] / f32 partials [4][32][48]
  int w = threadIdx.x >> 6;
  int lane = threadIdx.x & 63;
  int m = lane & 15, kg = lane >> 4;
  int r0 = blockIdx.x * 32;                  // 32 rows per block
  int cw = w * 128;                          // 128 cols per wave
  f32x4 acc[2][8];
#pragma unroll
  for (int a = 0; a < 2; a++)
#pragma unroll
    for (int t = 0; t < 8; t++)
#pragma unroll
      for (int r = 0; r < 4; r++) acc[a][t][r] = 0.0f;

  const float* xa0 = axg + (size_t)(r0 + m) * FIN + kg * 8;
  const float* xa1 = xa0 + 16 * FIN;
#pragma unroll
  for (int kc = 0; kc < 4; kc++) {
    int kb = kc * 32;
    u32x4 a0l = *(const u32x4*)(xa0 + kb);
    u32x4 a0h = *(const u32x4*)(xa0 + kb + 4);
    u32x4 a1l = *(const u32x4*)(xa1 + kb);
    u32x4 a1h = *(const u32x4*)(xa1 + kb + 4);
    bf16x8 a0 = pack8t(a0l, a0h);
    bf16x8 a1 = pack8t(a1l, a1h);
#pragma unroll
    for (int t = 0; t < 8; t++) {
      const unsigned short* bp = w1t + (size_t)(cw + t * 16 + m) * FIN + kb + kg * 8;
      bf16x8 b = __builtin_bit_cast(bf16x8, *(const ushort8*)bp);
      acc[0][t] = __builtin_amdgcn_mfma_f32_16x16x32_bf16(a0, b, acc[0][t], 0, 0, 0);
      acc[1][t] = __builtin_amdgcn_mfma_f32_16x16x32_bf16(a1, b, acc[1][t], 0, 0, 0);
    }
  }

  float bcol[8];
#pragma unroll
  for (int t = 0; t < 8; t++) bcol[t] = b1[cw + t * 16 + m];

  // per-row 16B mask segment covering this wave's 128 cols
  u32x4 mv[2][4];
#pragma unroll
  for (int rt = 0; rt < 2; rt++)
#pragma unroll
    for (int r = 0; r < 4; r++) {
      int row = r0 + rt * 16 + kg * 4 + r;
      mv[rt][r] = *(const u32x4*)(mask8 + (size_t)row * 64 + w * 16);
    }

  // epilogue: global f32 store + swizzled bf16 LDS stage
#pragma unroll
  for (int rt = 0; rt < 2; rt++)
#pragma unroll
    for (int t = 0; t < 8; t++)
#pragma unroll
      for (int r = 0; r < 4; r++) {
        int rowl = rt * 16 + kg * 4 + r;     // local row 0..31
        int col = cw + t * 16 + m;
        unsigned flat = (unsigned)(r0 + rowl) * FH + (unsigned)col;
        float v = fmaxf(acc[rt][t][r] + bcol[t], 0.0f);
        unsigned keep = (mv[rt][r][t >> 1] >> ((t & 1) * 16 + m)) & 1u;
        float hv = keep ? v * 2.0f : 0.0f;
        hidden[flat] = hv;
        unsigned short hb = (unsigned short)(__float_as_uint(hv) >> 16);  // trunc, = pack8t
        *(unsigned short*)(smem + rowl * 1024 + ((col * 2) ^ ((rowl & 15) << 4))) = hb;
      }
  __syncthreads();

  // phase 2: this wave contracts K slice [cw, cw+128) of the tile vs W2^T
  f32x4 acc2[2][3];
#pragma unroll
  for (int rt = 0; rt < 2; rt++)
#pragma unroll
    for (int t = 0; t < 3; t++)
#pragma unroll
      for (int r = 0; r < 4; r++) acc2[rt][t][r] = 0.0f;

#pragma unroll
  for (int kc = 0; kc < 4; kc++) {
    int colk = cw + kc * 32 + kg * 8;        // 8-col (16B) chunk, 16B-aligned
#pragma unroll
    for (int rt = 0; rt < 2; rt++) {
      int rowl = rt * 16 + m;                // A[m][k]: m = hidden row
      bf16x8 a = *(const bf16x8*)(smem + rowl * 1024 + ((colk * 2) ^ ((rowl & 15) << 4)));
#pragma unroll
      for (int t = 0; t < 3; t++) {
        bf16x8 b = __builtin_bit_cast(bf16x8,
            *(const ushort8*)(w2t + (size_t)(t * 16 + m) * FH + colk));
        acc2[rt][t] = __builtin_amdgcn_mfma_f32_16x16x32_bf16(a, b, acc2[rt][t], 0, 0, 0);
      }
    }
  }
  __syncthreads();                           // all tile reads done before overwrite

  // phase 3: cross-wave K-reduction via LDS partials [4][32][48]
  float* part = (float*)smem;
#pragma unroll
  for (int rt = 0; rt < 2; rt++)
#pragma unroll
    for (int t = 0; t < 3; t++)
#pragma unroll
      for (int r = 0; r < 4; r++) {
        int rowl = rt * 16 + kg * 4 + r;
        int coln = t * 16 + m;
        part[w * 1536 + rowl * 48 + coln] = acc2[rt][t][r];
      }
  __syncthreads();

  for (int idx = threadIdx.x; idx < 1536; idx += 256) {
    int rowl = idx / 48, coln = idx - rowl * 48;
    float s = part[idx] + part[1536 + idx] + part[3072 + idx] + part[4608 + idx];
    if (coln < FO) h2[(size_t)(r0 + rowl) * FO + coln] = s;
  }
}

// ---------------- aggregate L2 + bias -> out (f32); h2 = 16 MB, LLC-resident ----------------

__global__ __launch_bounds__(256) void k_agg2(const float* __restrict__ h2,
                                              const int* __restrict__ rowptr,
                                              const int* __restrict__ src_sorted,
                                              const float* __restrict__ dinv_src,
                                              const float* __restrict__ dinv,
                                              const float* __restrict__ b2,
                                              float* __restrict__ out) {
  int i = blockIdx.x * 4 + (threadIdx.x >> 6);
  int lane = threadIdx.x & 63;
  int rs = rowptr[i], re = rowptr[i + 1];
  float di = dinv[i];
  float acc = 0.0f;

  for (int base = rs; base < re; base += 64) {
    int n = re - base; if (n > 64) n = 64;
    int myi = 0; float myw = 0.0f;
    if (lane < n) {
      myi = __builtin_nontemporal_load(&src_sorted[base + lane]);
      myw = __builtin_nontemporal_load(&dinv_src[base + lane]);
    }
    for (int j = 0; j < n; j++) {
      int s = __shfl(myi, j);
      float wgt = __shfl(myw, j);
      if (lane < FO) acc += wgt * h2[(size_t)s * FO + lane];
    }
  }
  if (lane < FO) {
    acc += di * h2[(size_t)i * FO + lane];
    out[(size_t)i * FO + lane] = acc * di + b2[lane];
  }
}

// ---------------- launcher ----------------

extern "C" void kernel_launch(void* const* d_in, const int* in_sizes, int n_in,
                              void* d_out, int out_size, void* d_ws, size_t ws_size,
                              hipStream_t stream) {
  const float* x  = (const float*)d_in[0];
  const int* ei   = (const int*)d_in[1];
  const float* w1 = (const float*)d_in[2];
  const float* b1 = (const float*)d_in[3];
  const float* w2 = (const float*)d_in[4];
  const float* b2 = (const float*)d_in[5];

  char* ws = (char*)d_ws;
  float* dinv            = (float*)(ws + O_DINV);
  int* cnt               = (int*)(ws + O_CNT);
  int* rowptr            = (int*)(ws + O_ROWPTR);
  int* cur               = (int*)(ws + O_CUR);
  int* src_sorted        = (int*)(ws + O_SRC);
  float* dinv_src        = (float*)(ws + O_DSRC);
  unsigned short* w1t    = (unsigned short*)(ws + O_W1T);
  unsigned short* w2t    = (unsigned short*)(ws + O_W2T);
  float* axg             = (float*)(ws + O_AXG);
  float* h2              = (float*)(ws + O_H2);
  unsigned char* mask8   = (unsigned char*)(ws + O_MASK);
  int* partials          = (int*)(ws + O_PART);

  float* outp   = (float*)d_out;                       // [N,40]
  float* hidden = outp + (size_t)N_NODES * FO;         // [N,512]

  const int* srcA = ei;             // edge_index[0]
  const int* dstA = ei + N_EDGES;   // edge_index[1]

  hipMemsetAsync(cnt, 0, N_NODES * sizeof(int), stream);
  k_count<<<(N_EDGES + 255) / 256, 256, 0, stream>>>(dstA, cnt);
  k_scan1tw<<<NCHUNK + TWBLKS, 256, 0, stream>>>(cnt, rowptr, partials, dinv,
                                                 w1, w2, w1t, w2t);
  k_scan3<<<NCHUNK, 256, 0, stream>>>(rowptr, partials, cur);
  k_scatter<<<(N_EDGES + 255) / 256, 256, 0, stream>>>(srcA, dstA, dinv, cur,
                                                       src_sorted, dinv_src);
  k_aggx<<<N_NODES / 4, 256, 0, stream>>>(x, rowptr, src_sorted, dinv_src, dinv,
                                          axg, mask8);
  k_gemm12<<<N_NODES / 32, 256, 0, stream>>>(axg, w1t, b1, mask8, w2t, hidden, h2);
  k_agg2<<<N_NODES / 4, 256, 0, stream>>>(h2, rowptr, src_sorted, dinv_src, dinv,
                                          b2, outp);
}

// Round 5
// 608.229 us; speedup vs baseline: 1.0887x; 1.0249x over previous
//
#include <hip/hip_runtime.h>
#include <hip/hip_bf16.h>
#include <stdint.h>

typedef __attribute__((ext_vector_type(8))) __bf16 bf16x8;
typedef __attribute__((ext_vector_type(8))) unsigned short ushort8;
typedef __attribute__((ext_vector_type(4))) float f32x4;
typedef __attribute__((ext_vector_type(4))) unsigned int u32x4;

#define N_NODES 100000
#define N_EDGES 800000
#define FIN 128
#define FH 512
#define FO 40
#define NCHUNK 391   // ceil(N/256)
#define TWBLKS 352   // (128*512 + 48*512)/256

// workspace byte offsets (16B-aligned where vector loads occur)
#define O_DINV   0ull            // N floats
#define O_CNT    400000ull       // N ints
#define O_ROWPTR 800000ull       // N+1 ints
#define O_CUR    1200016ull      // N ints
#define O_SRC    1600016ull      // E ints   (src sorted by dst)
#define O_DSRC   4800016ull      // E floats (dinv[src] sorted by dst)
#define O_W1T    8000016ull      // 512x128 bf16
#define O_W2T    8131088ull      // 48x512 bf16 (zero-padded cols 40..47)
#define O_AXG    8180240ull      // N x 128 f32  (aggregated x)
#define O_H2     59380240ull     // N x 40 f32 (written by fused gemm, read by agg2)
#define O_PART   75380240ull     // 512 ints
#define O_MASK   75400000ull     // N x 64 B packed dropout mask (6.4 MB)

__device__ __forceinline__ unsigned short f2bf(float f) {
  unsigned u = __float_as_uint(f);
  u += 0x7fffu + ((u >> 16) & 1u);           // round-to-nearest-even
  return (unsigned short)(u >> 16);
}

// truncating f32x8 -> bf16x8 pack from registers (staging for MFMA A)
__device__ __forceinline__ bf16x8 pack8t(u32x4 a, u32x4 b) {
  u32x4 w;
  w.x = __builtin_amdgcn_perm(a.y, a.x, 0x07060302u);
  w.y = __builtin_amdgcn_perm(a.w, a.z, 0x07060302u);
  w.z = __builtin_amdgcn_perm(b.y, b.x, 0x07060302u);
  w.w = __builtin_amdgcn_perm(b.w, b.z, 0x07060302u);
  return __builtin_bit_cast(bf16x8, w);
}

// ---------------- degree count ----------------

__global__ __launch_bounds__(256) void k_count(const int* __restrict__ dst,
                                               int* __restrict__ cnt) {
  int e = blockIdx.x * 256 + threadIdx.x;
  if (e < N_EDGES) atomicAdd(&cnt[__builtin_nontemporal_load(&dst[e])], 1);
}

// ---------------- scan chunk-local + dinv + weight transposes, fused ----------------

__global__ __launch_bounds__(256) void k_scan1tw(const int* __restrict__ cnt,
                                                 int* __restrict__ rowptr,
                                                 int* __restrict__ partials,
                                                 float* __restrict__ dinv,
                                                 const float* __restrict__ w1,
                                                 const float* __restrict__ w2,
                                                 unsigned short* __restrict__ w1t,
                                                 unsigned short* __restrict__ w2t) {
  int b = blockIdx.x;
  if (b >= NCHUNK) {                         // weight-transpose blocks
    int t = (b - NCHUNK) * 256 + threadIdx.x;
    if (t < FIN * FH) {                      // W1^T: [512c][128k]
      int c = t >> 7, k = t & 127;
      w1t[c * 128 + k] = f2bf(w1[k * FH + c]);
    } else {                                 // W2^T: [48c][512k], pad c>=40
      int u = t - FIN * FH;
      int c = u >> 9, k = u & 511;
      w2t[c * FH + k] = (c < FO) ? f2bf(w2[k * FO + c]) : (unsigned short)0;
    }
    return;
  }
  int t = threadIdx.x, g = b * 256 + t;
  int v = (g < N_NODES) ? cnt[g] : 0;
  if (g < N_NODES) dinv[g] = __frsqrt_rn((float)(v + 1));
  int lane = t & 63, w = t >> 6;
  int sc = v;
#pragma unroll
  for (int off = 1; off < 64; off <<= 1) {
    int u = __shfl_up(sc, off);
    if (lane >= off) sc += u;
  }
  __shared__ int wsum[4];
  if (lane == 63) wsum[w] = sc;
  __syncthreads();
  int add = 0;
  for (int j = 0; j < w; j++) add += wsum[j];
  int incl = sc + add;
  if (g < N_NODES) rowptr[g] = incl - v;     // chunk-local exclusive
  if (t == 255) partials[b] = incl;
}

// ---------------- global scan offsets + cur init ----------------

__global__ __launch_bounds__(256) void k_scan3(int* __restrict__ rowptr,
                                               const int* __restrict__ partials,
                                               int* __restrict__ cur) {
  __shared__ int sbase;
  int t = threadIdx.x;
  int chunk = blockIdx.x;
  if (t < 64) {                              // wave 0: base = sum partials[0..chunk)
    int s = 0;
    for (int j = t; j < chunk; j += 64) s += partials[j];
#pragma unroll
    for (int off = 32; off; off >>= 1) s += __shfl_down(s, off);
    if (t == 0) sbase = s;
  }
  __syncthreads();
  int base = sbase;
  int g = chunk * 256 + t;
  if (g < N_NODES) {
    int v = rowptr[g] + base;
    rowptr[g] = v;
    cur[g] = v;
  } else if (g == N_NODES) {
    rowptr[N_NODES] = N_EDGES;
  }
}

__global__ __launch_bounds__(256) void k_scatter(const int* __restrict__ src,
                                                 const int* __restrict__ dst,
                                                 const float* __restrict__ dinv,
                                                 int* __restrict__ cur,
                                                 int* __restrict__ src_sorted,
                                                 float* __restrict__ dinv_src) {
  int e = blockIdx.x * 256 + threadIdx.x;
  if (e < N_EDGES) {
    int s = __builtin_nontemporal_load(&src[e]);
    int d = __builtin_nontemporal_load(&dst[e]);
    int pos = atomicAdd(&cur[d], 1);
    src_sorted[pos] = s;
    dinv_src[pos] = dinv[s];
  }
}

// ---------------- dropout bits (JAX partitionable threefry, key=42) ----------------

__device__ __forceinline__ unsigned tf_bits(unsigned x0, unsigned x1) {
  const unsigned K0 = 0u, K1 = 42u, K2 = 0x1BD11BDAu ^ 42u;
  x0 += K0; x1 += K1;
#define RND(r) { x0 += x1; x1 = (x1 << (r)) | (x1 >> (32 - (r))); x1 ^= x0; }
  RND(13) RND(15) RND(26) RND(6)
  x0 += K1; x1 += K2 + 1u;
  RND(17) RND(29) RND(16) RND(24)
  x0 += K2; x1 += K0 + 2u;
  RND(13) RND(15) RND(26) RND(6)
  x0 += K0; x1 += K1 + 3u;
  RND(17) RND(29) RND(16) RND(24)
  x0 += K1; x1 += K2 + 4u;
  RND(13) RND(15) RND(26) RND(6)
  x0 += K2; x1 += K0 + 5u;
#undef RND
  return x0 ^ x1;   // partitionable path xor-folds (out0, out1)
}

// ---------------- aggregate x + dropout-mask generation, fused ----------------
// axg = D^-1/2 (A+I) D^-1/2 x  (commuted vs reference: (A(XW1)) == (AX)W1).
// One wave per node; the wave also generates node i's 512 packed mask bits.
// Mask layout: byte row*64 + (col>>3), bit (col&7).

__global__ __launch_bounds__(256) void k_aggx(const float* __restrict__ x,
                                              const int* __restrict__ rowptr,
                                              const int* __restrict__ src_sorted,
                                              const float* __restrict__ dinv_src,
                                              const float* __restrict__ dinv,
                                              float* __restrict__ axg,
                                              unsigned char* __restrict__ mask8) {
  int i = blockIdx.x * 4 + (threadIdx.x >> 6);
  int lane = threadIdx.x & 63;
  int rs = rowptr[i], re = rowptr[i + 1];
  float di = dinv[i];
  int c = lane << 1;                         // 2 channels per lane

  // dropout mask for row i (independent -> fills gather-stall slots)
  {
    unsigned fb = (unsigned)i * FH + ((unsigned)lane << 3);
    unsigned mb = 0;
#pragma unroll
    for (int q = 0; q < 8; q++)
      mb |= ((~tf_bits(0u, fb + q)) >> 31) << q;   // keep iff top bit == 0
    mask8[((size_t)i << 6) | lane] = (unsigned char)mb;
  }

  float a0 = 0.0f, a1 = 0.0f;

  for (int base = rs; base < re; base += 64) {
    int n = re - base; if (n > 64) n = 64;
    int myi = 0; float myw = 0.0f;
    if (lane < n) {
      myi = src_sorted[base + lane];
      myw = dinv_src[base + lane];
    }
    int j = 0;
    for (; j + 4 <= n; j += 4) {             // 4 gathers in flight
      int s0 = __shfl(myi, j),     s1 = __shfl(myi, j + 1);
      int s2 = __shfl(myi, j + 2), s3 = __shfl(myi, j + 3);
      float w0 = __shfl(myw, j),      w1_ = __shfl(myw, j + 1);
      float w2_ = __shfl(myw, j + 2), w3_ = __shfl(myw, j + 3);
      float2 v0 = *(const float2*)(x + (((size_t)s0 << 7) | c));
      float2 v1 = *(const float2*)(x + (((size_t)s1 << 7) | c));
      float2 v2 = *(const float2*)(x + (((size_t)s2 << 7) | c));
      float2 v3 = *(const float2*)(x + (((size_t)s3 << 7) | c));
      a0 += w0 * v0.x + w1_ * v1.x + w2_ * v2.x + w3_ * v3.x;
      a1 += w0 * v0.y + w1_ * v1.y + w2_ * v2.y + w3_ * v3.y;
    }
    for (; j < n; j++) {
      int s0 = __shfl(myi, j);
      float w0 = __shfl(myw, j);
      float2 v0 = *(const float2*)(x + (((size_t)s0 << 7) | c));
      a0 += w0 * v0.x; a1 += w0 * v0.y;
    }
  }
  { // self loop, weight di
    float2 vs = *(const float2*)(x + (((size_t)i << 7) | c));
    a0 += di * vs.x; a1 += di * vs.y;
  }
  float2 o; o.x = a0 * di; o.y = a1 * di;
  *(float2*)(axg + (((size_t)i << 7) | c)) = o;
}

// ---------------- FUSED GEMM1+GEMM2 ----------------
// Phase 1: hidden = dropout(relu(axg @ W1 + b1))  [32 rows x 512 cols per block]
//   - stores f32 hidden to global (mandatory output)
//   - stages truncated-bf16 hidden into a 32 KB LDS tile (bit-identical to the
//     old pack8t path), XOR-swizzled byte ^= (row&15)<<4 so phase-2
//     ds_read_b128 spreads 4 lanes per 16B slot -> conflict-free.
// Phase 2: each wave contracts its own K=128 slice vs W2^T -> 32x48 partial.
// Phase 3: cross-wave reduce in (reused) LDS, write h2[32][40].

__global__ __launch_bounds__(256) void k_gemm12(const float* __restrict__ axg,
                                                const unsigned short* __restrict__ w1t,
                                                const float* __restrict__ b1,
                                                const unsigned char* __restrict__ mask8,
                                                const unsigned short* __restrict__ w2t,
                                                float* __restrict__ hidden,
                                                float* __restrict__ h2) {
  __shared__ __align__(16) char smem[32768];   // bf16 tile [32][512] / f32 partials [4][32][48]
  int w = threadIdx.x >> 6;
  int lane = threadIdx.x & 63;
  int m = lane & 15, kg = lane >> 4;
  int r0 = blockIdx.x * 32;                  // 32 rows per block
  int cw = w * 128;                          // 128 cols per wave
  f32x4 acc[2][8];
#pragma unroll
  for (int a = 0; a < 2; a++)
#pragma unroll
    for (int t = 0; t < 8; t++)
#pragma unroll
      for (int r = 0; r < 4; r++) acc[a][t][r] = 0.0f;

  const float* xa0 = axg + (size_t)(r0 + m) * FIN + kg * 8;
  const float* xa1 = xa0 + 16 * FIN;
#pragma unroll
  for (int kc = 0; kc < 4; kc++) {
    int kb = kc * 32;
    u32x4 a0l = *(const u32x4*)(xa0 + kb);
    u32x4 a0h = *(const u32x4*)(xa0 + kb + 4);
    u32x4 a1l = *(const u32x4*)(xa1 + kb);
    u32x4 a1h = *(const u32x4*)(xa1 + kb + 4);
    bf16x8 a0 = pack8t(a0l, a0h);
    bf16x8 a1 = pack8t(a1l, a1h);
#pragma unroll
    for (int t = 0; t < 8; t++) {
      const unsigned short* bp = w1t + (size_t)(cw + t * 16 + m) * FIN + kb + kg * 8;
      bf16x8 b = __builtin_bit_cast(bf16x8, *(const ushort8*)bp);
      acc[0][t] = __builtin_amdgcn_mfma_f32_16x16x32_bf16(a0, b, acc[0][t], 0, 0, 0);
      acc[1][t] = __builtin_amdgcn_mfma_f32_16x16x32_bf16(a1, b, acc[1][t], 0, 0, 0);
    }
  }

  float bcol[8];
#pragma unroll
  for (int t = 0; t < 8; t++) bcol[t] = b1[cw + t * 16 + m];

  // per-row 16B mask segment covering this wave's 128 cols
  u32x4 mv[2][4];
#pragma unroll
  for (int rt = 0; rt < 2; rt++)
#pragma unroll
    for (int r = 0; r < 4; r++) {
      int row = r0 + rt * 16 + kg * 4 + r;
      mv[rt][r] = *(const u32x4*)(mask8 + (size_t)row * 64 + w * 16);
    }

  // epilogue: global f32 store + swizzled bf16 LDS stage
#pragma unroll
  for (int rt = 0; rt < 2; rt++)
#pragma unroll
    for (int t = 0; t < 8; t++)
#pragma unroll
      for (int r = 0; r < 4; r++) {
        int rowl = rt * 16 + kg * 4 + r;     // local row 0..31
        int col = cw + t * 16 + m;
        unsigned flat = (unsigned)(r0 + rowl) * FH + (unsigned)col;
        float v = fmaxf(acc[rt][t][r] + bcol[t], 0.0f);
        unsigned keep = (mv[rt][r][t >> 1] >> ((t & 1) * 16 + m)) & 1u;
        float hv = keep ? v * 2.0f : 0.0f;
        hidden[flat] = hv;
        unsigned short hb = (unsigned short)(__float_as_uint(hv) >> 16);  // trunc, = pack8t
        *(unsigned short*)(smem + rowl * 1024 + ((col * 2) ^ ((rowl & 15) << 4))) = hb;
      }
  __syncthreads();

  // phase 2: this wave contracts K slice [cw, cw+128) of the tile vs W2^T
  f32x4 acc2[2][3];
#pragma unroll
  for (int rt = 0; rt < 2; rt++)
#pragma unroll
    for (int t = 0; t < 3; t++)
#pragma unroll
      for (int r = 0; r < 4; r++) acc2[rt][t][r] = 0.0f;

#pragma unroll
  for (int kc = 0; kc < 4; kc++) {
    int colk = cw + kc * 32 + kg * 8;        // 8-col (16B) chunk, 16B-aligned
#pragma unroll
    for (int rt = 0; rt < 2; rt++) {
      int rowl = rt * 16 + m;                // A[m][k]: m = hidden row
      bf16x8 a = *(const bf16x8*)(smem + rowl * 1024 + ((colk * 2) ^ ((rowl & 15) << 4)));
#pragma unroll
      for (int t = 0; t < 3; t++) {
        bf16x8 b = __builtin_bit_cast(bf16x8,
            *(const ushort8*)(w2t + (size_t)(t * 16 + m) * FH + colk));
        acc2[rt][t] = __builtin_amdgcn_mfma_f32_16x16x32_bf16(a, b, acc2[rt][t], 0, 0, 0);
      }
    }
  }
  __syncthreads();                           // all tile reads done before overwrite

  // phase 3: cross-wave K-reduction via LDS partials [4][32][48]
  float* part = (float*)smem;
#pragma unroll
  for (int rt = 0; rt < 2; rt++)
#pragma unroll
    for (int t = 0; t < 3; t++)
#pragma unroll
      for (int r = 0; r < 4; r++) {
        int rowl = rt * 16 + kg * 4 + r;
        int coln = t * 16 + m;
        part[w * 1536 + rowl * 48 + coln] = acc2[rt][t][r];
      }
  __syncthreads();

  for (int idx = threadIdx.x; idx < 1536; idx += 256) {
    int rowl = idx / 48, coln = idx - rowl * 48;
    float s = part[idx] + part[1536 + idx] + part[3072 + idx] + part[4608 + idx];
    if (coln < FO) h2[(size_t)(r0 + rowl) * FO + coln] = s;
  }
}

// ---------------- aggregate L2 + bias -> out (f32) ----------------
// RESTRUCTURED (round 5): one THREAD per (node, channel) instead of one wave
// per node. The old form serialized one edge per wave-step via __shfl with
// 40/64 lanes active (~800K serial L2-latency steps). Here 4M independent
// threads each do ~deg(i) independent 4 B gathers from the 16 MB L2/L3-resident
// h2 -- latency hidden by TLP alone. Block = 320 threads = exactly 8 nodes.
// Edge-list loads are same-address within a 40-lane node group -> broadcast.

__global__ __launch_bounds__(320) void k_agg2(const float* __restrict__ h2,
                                              const int* __restrict__ rowptr,
                                              const int* __restrict__ src_sorted,
                                              const float* __restrict__ dinv_src,
                                              const float* __restrict__ dinv,
                                              const float* __restrict__ b2,
                                              float* __restrict__ out) {
  int i = blockIdx.x * 8 + threadIdx.x / 40;   // node
  int ch = threadIdx.x % 40;                   // output channel
  int rs = rowptr[i], re = rowptr[i + 1];
  float di = dinv[i];
  float acc = 0.0f;

  int e = rs;
  for (; e + 2 <= re; e += 2) {                // 2 gathers in flight
    int s0 = src_sorted[e], s1 = src_sorted[e + 1];
    float w0 = dinv_src[e], w1_ = dinv_src[e + 1];
    float v0 = h2[(size_t)s0 * FO + ch];
    float v1 = h2[(size_t)s1 * FO + ch];
    acc += w0 * v0 + w1_ * v1;
  }
  if (e < re) {
    acc += dinv_src[e] * h2[(size_t)src_sorted[e] * FO + ch];
  }
  acc += di * h2[(size_t)i * FO + ch];         // self loop
  out[(size_t)i * FO + ch] = acc * di + b2[ch];
}

// ---------------- launcher ----------------

extern "C" void kernel_launch(void* const* d_in, const int* in_sizes, int n_in,
                              void* d_out, int out_size, void* d_ws, size_t ws_size,
                              hipStream_t stream) {
  const float* x  = (const float*)d_in[0];
  const int* ei   = (const int*)d_in[1];
  const float* w1 = (const float*)d_in[2];
  const float* b1 = (const float*)d_in[3];
  const float* w2 = (const float*)d_in[4];
  const float* b2 = (const float*)d_in[5];

  char* ws = (char*)d_ws;
  float* dinv            = (float*)(ws + O_DINV);
  int* cnt               = (int*)(ws + O_CNT);
  int* rowptr            = (int*)(ws + O_ROWPTR);
  int* cur               = (int*)(ws + O_CUR);
  int* src_sorted        = (int*)(ws + O_SRC);
  float* dinv_src        = (float*)(ws + O_DSRC);
  unsigned short* w1t    = (unsigned short*)(ws + O_W1T);
  unsigned short* w2t    = (unsigned short*)(ws + O_W2T);
  float* axg             = (float*)(ws + O_AXG);
  float* h2              = (float*)(ws + O_H2);
  unsigned char* mask8   = (unsigned char*)(ws + O_MASK);
  int* partials          = (int*)(ws + O_PART);

  float* outp   = (float*)d_out;                       // [N,40]
  float* hidden = outp + (size_t)N_NODES * FO;         // [N,512]

  const int* srcA = ei;             // edge_index[0]
  const int* dstA = ei + N_EDGES;   // edge_index[1]

  hipMemsetAsync(cnt, 0, N_NODES * sizeof(int), stream);
  k_count<<<(N_EDGES + 255) / 256, 256, 0, stream>>>(dstA, cnt);
  k_scan1tw<<<NCHUNK + TWBLKS, 256, 0, stream>>>(cnt, rowptr, partials, dinv,
                                                 w1, w2, w1t, w2t);
  k_scan3<<<NCHUNK, 256, 0, stream>>>(rowptr, partials, cur);
  k_scatter<<<(N_EDGES + 255) / 256, 256, 0, stream>>>(srcA, dstA, dinv, cur,
                                                       src_sorted, dinv_src);
  k_aggx<<<N_NODES / 4, 256, 0, stream>>>(x, rowptr, src_sorted, dinv_src, dinv,
                                          axg, mask8);
  k_gemm12<<<N_NODES / 32, 256, 0, stream>>>(axg, w1t, b1, mask8, w2t, hidden, h2);
  k_agg2<<<N_NODES / 8, 320, 0, stream>>>(h2, rowptr, src_sorted, dinv_src, dinv,
                                          b2, outp);
}

// Round 6
// 571.843 us; speedup vs baseline: 1.1579x; 1.0636x over previous
//
#include <hip/hip_runtime.h>
#include <hip/hip_bf16.h>
#include <stdint.h>

typedef __attribute__((ext_vector_type(8))) __bf16 bf16x8;
typedef __attribute__((ext_vector_type(8))) unsigned short ushort8;
typedef __attribute__((ext_vector_type(4))) float f32x4;
typedef __attribute__((ext_vector_type(4))) unsigned int u32x4;

#define N_NODES 100000
#define N_EDGES 800000
#define FIN 128
#define FH 512
#define FO 40
#define NCHUNK 391   // ceil(N/256)
#define TWBLKS 352   // (128*512 + 48*512)/256

// workspace byte offsets (16B-aligned where vector loads occur)
#define O_DINV   0ull            // N floats
#define O_CNT    400000ull       // N ints
#define O_ROWPTR 800000ull       // N+1 ints
#define O_CUR    1200016ull      // N ints
#define O_SRC    1600016ull      // E ints   (src sorted by dst)
#define O_DSRC   4800016ull      // E floats (dinv[src] sorted by dst)
#define O_W1T    8000016ull      // 512x128 bf16
#define O_W2T    8131088ull      // 48x512 bf16 (zero-padded cols 40..47)
#define O_AXG    8180240ull      // N x 128 f32  (aggregated x)
#define O_H2     59380240ull     // N x 40 f32 (written by fused gemm, read by agg2)
#define O_PART   75380240ull     // 512 ints
#define O_MASK   75400000ull     // N x 64 B packed dropout mask (6.4 MB)

__device__ __forceinline__ unsigned short f2bf(float f) {
  unsigned u = __float_as_uint(f);
  u += 0x7fffu + ((u >> 16) & 1u);           // round-to-nearest-even
  return (unsigned short)(u >> 16);
}

// truncating f32x8 -> bf16x8 pack from registers (staging for MFMA A)
__device__ __forceinline__ bf16x8 pack8t(u32x4 a, u32x4 b) {
  u32x4 w;
  w.x = __builtin_amdgcn_perm(a.y, a.x, 0x07060302u);
  w.y = __builtin_amdgcn_perm(a.w, a.z, 0x07060302u);
  w.z = __builtin_amdgcn_perm(b.y, b.x, 0x07060302u);
  w.w = __builtin_amdgcn_perm(b.w, b.z, 0x07060302u);
  return __builtin_bit_cast(bf16x8, w);
}

// ---------------- degree count ----------------

__global__ __launch_bounds__(256) void k_count(const int* __restrict__ dst,
                                               int* __restrict__ cnt) {
  int e = blockIdx.x * 256 + threadIdx.x;
  if (e < N_EDGES) atomicAdd(&cnt[__builtin_nontemporal_load(&dst[e])], 1);
}

// ---------------- scan chunk-local + dinv + weight transposes, fused ----------------

__global__ __launch_bounds__(256) void k_scan1tw(const int* __restrict__ cnt,
                                                 int* __restrict__ rowptr,
                                                 int* __restrict__ partials,
                                                 float* __restrict__ dinv,
                                                 const float* __restrict__ w1,
                                                 const float* __restrict__ w2,
                                                 unsigned short* __restrict__ w1t,
                                                 unsigned short* __restrict__ w2t) {
  int b = blockIdx.x;
  if (b >= NCHUNK) {                         // weight-transpose blocks
    int t = (b - NCHUNK) * 256 + threadIdx.x;
    if (t < FIN * FH) {                      // W1^T: [512c][128k]
      int c = t >> 7, k = t & 127;
      w1t[c * 128 + k] = f2bf(w1[k * FH + c]);
    } else {                                 // W2^T: [48c][512k], pad c>=40
      int u = t - FIN * FH;
      int c = u >> 9, k = u & 511;
      w2t[c * FH + k] = (c < FO) ? f2bf(w2[k * FO + c]) : (unsigned short)0;
    }
    return;
  }
  int t = threadIdx.x, g = b * 256 + t;
  int v = (g < N_NODES) ? cnt[g] : 0;
  if (g < N_NODES) dinv[g] = __frsqrt_rn((float)(v + 1));
  int lane = t & 63, w = t >> 6;
  int sc = v;
#pragma unroll
  for (int off = 1; off < 64; off <<= 1) {
    int u = __shfl_up(sc, off);
    if (lane >= off) sc += u;
  }
  __shared__ int wsum[4];
  if (lane == 63) wsum[w] = sc;
  __syncthreads();
  int add = 0;
  for (int j = 0; j < w; j++) add += wsum[j];
  int incl = sc + add;
  if (g < N_NODES) rowptr[g] = incl - v;     // chunk-local exclusive
  if (t == 255) partials[b] = incl;
}

// ---------------- global scan offsets + cur init ----------------

__global__ __launch_bounds__(256) void k_scan3(int* __restrict__ rowptr,
                                               const int* __restrict__ partials,
                                               int* __restrict__ cur) {
  __shared__ int sbase;
  int t = threadIdx.x;
  int chunk = blockIdx.x;
  if (t < 64) {                              // wave 0: base = sum partials[0..chunk)
    int s = 0;
    for (int j = t; j < chunk; j += 64) s += partials[j];
#pragma unroll
    for (int off = 32; off; off >>= 1) s += __shfl_down(s, off);
    if (t == 0) sbase = s;
  }
  __syncthreads();
  int base = sbase;
  int g = chunk * 256 + t;
  if (g < N_NODES) {
    int v = rowptr[g] + base;
    rowptr[g] = v;
    cur[g] = v;
  } else if (g == N_NODES) {
    rowptr[N_NODES] = N_EDGES;
  }
}

__global__ __launch_bounds__(256) void k_scatter(const int* __restrict__ src,
                                                 const int* __restrict__ dst,
                                                 const float* __restrict__ dinv,
                                                 int* __restrict__ cur,
                                                 int* __restrict__ src_sorted,
                                                 float* __restrict__ dinv_src) {
  int e = blockIdx.x * 256 + threadIdx.x;
  if (e < N_EDGES) {
    int s = __builtin_nontemporal_load(&src[e]);
    int d = __builtin_nontemporal_load(&dst[e]);
    int pos = atomicAdd(&cur[d], 1);
    src_sorted[pos] = s;
    dinv_src[pos] = dinv[s];
  }
}

// ---------------- dropout bits (JAX partitionable threefry, key=42) ----------------

__device__ __forceinline__ unsigned tf_bits(unsigned x0, unsigned x1) {
  const unsigned K0 = 0u, K1 = 42u, K2 = 0x1BD11BDAu ^ 42u;
  x0 += K0; x1 += K1;
#define RND(r) { x0 += x1; x1 = (x1 << (r)) | (x1 >> (32 - (r))); x1 ^= x0; }
  RND(13) RND(15) RND(26) RND(6)
  x0 += K1; x1 += K2 + 1u;
  RND(17) RND(29) RND(16) RND(24)
  x0 += K2; x1 += K0 + 2u;
  RND(13) RND(15) RND(26) RND(6)
  x0 += K0; x1 += K1 + 3u;
  RND(17) RND(29) RND(16) RND(24)
  x0 += K1; x1 += K2 + 4u;
  RND(13) RND(15) RND(26) RND(6)
  x0 += K2; x1 += K0 + 5u;
#undef RND
  return x0 ^ x1;   // partitionable path xor-folds (out0, out1)
}

// ---------------- aggregate x + dropout-mask generation, fused ----------------
// axg = D^-1/2 (A+I) D^-1/2 x  (commuted vs reference: (A(XW1)) == (AX)W1).
// One wave per node; the wave also generates node i's 512 packed mask bits.
// Mask layout: byte row*64 + (col>>3), bit (col&7).

__global__ __launch_bounds__(256) void k_aggx(const float* __restrict__ x,
                                              const int* __restrict__ rowptr,
                                              const int* __restrict__ src_sorted,
                                              const float* __restrict__ dinv_src,
                                              const float* __restrict__ dinv,
                                              float* __restrict__ axg,
                                              unsigned char* __restrict__ mask8) {
  int i = blockIdx.x * 4 + (threadIdx.x >> 6);
  int lane = threadIdx.x & 63;
  int rs = rowptr[i], re = rowptr[i + 1];
  float di = dinv[i];
  int c = lane << 1;                         // 2 channels per lane

  // dropout mask for row i (independent -> fills gather-stall slots)
  {
    unsigned fb = (unsigned)i * FH + ((unsigned)lane << 3);
    unsigned mb = 0;
#pragma unroll
    for (int q = 0; q < 8; q++)
      mb |= ((~tf_bits(0u, fb + q)) >> 31) << q;   // keep iff top bit == 0
    mask8[((size_t)i << 6) | lane] = (unsigned char)mb;
  }

  float a0 = 0.0f, a1 = 0.0f;

  for (int base = rs; base < re; base += 64) {
    int n = re - base; if (n > 64) n = 64;
    int myi = 0; float myw = 0.0f;
    if (lane < n) {
      myi = src_sorted[base + lane];
      myw = dinv_src[base + lane];
    }
    int j = 0;
    for (; j + 4 <= n; j += 4) {             // 4 gathers in flight
      int s0 = __shfl(myi, j),     s1 = __shfl(myi, j + 1);
      int s2 = __shfl(myi, j + 2), s3 = __shfl(myi, j + 3);
      float w0 = __shfl(myw, j),      w1_ = __shfl(myw, j + 1);
      float w2_ = __shfl(myw, j + 2), w3_ = __shfl(myw, j + 3);
      float2 v0 = *(const float2*)(x + (((size_t)s0 << 7) | c));
      float2 v1 = *(const float2*)(x + (((size_t)s1 << 7) | c));
      float2 v2 = *(const float2*)(x + (((size_t)s2 << 7) | c));
      float2 v3 = *(const float2*)(x + (((size_t)s3 << 7) | c));
      a0 += w0 * v0.x + w1_ * v1.x + w2_ * v2.x + w3_ * v3.x;
      a1 += w0 * v0.y + w1_ * v1.y + w2_ * v2.y + w3_ * v3.y;
    }
    for (; j < n; j++) {
      int s0 = __shfl(myi, j);
      float w0 = __shfl(myw, j);
      float2 v0 = *(const float2*)(x + (((size_t)s0 << 7) | c));
      a0 += w0 * v0.x; a1 += w0 * v0.y;
    }
  }
  { // self loop, weight di
    float2 vs = *(const float2*)(x + (((size_t)i << 7) | c));
    a0 += di * vs.x; a1 += di * vs.y;
  }
  float2 o; o.x = a0 * di; o.y = a1 * di;
  *(float2*)(axg + (((size_t)i << 7) | c)) = o;
}

// ---------------- FUSED GEMM1+GEMM2 ----------------
// Phase 1 (ROUND 6 CHANGE): operands of the 16x16x32 MFMA are SWAPPED --
// mfma(w1_frag, axg_frag, acc) computes the transposed fragment, so the C/D
// layout (col=lane&15, row=(lane>>4)*4+reg; m89/m91-verified) lands with
// col -> hidden-ROW (= m) and reg -> 4 CONTIGUOUS hidden-cols (kg*4+r).
// Epilogue therefore stores hidden with 16 nontemporal global_store_dwordx4
// per thread instead of 64 scalar 4 B stores (the old pattern measured only
// ~1.4 TB/s write throughput vs the fill's 5.9 -- store-request-bound).
// Phase 2/3 unchanged: LDS bf16 tile (same XOR swizzle involution, now
// written as 8 B chunks), per-wave K=128 slice vs W2^T, cross-wave reduce.

__global__ __launch_bounds__(256) void k_gemm12(const float* __restrict__ axg,
                                                const unsigned short* __restrict__ w1t,
                                                const float* __restrict__ b1,
                                                const unsigned char* __restrict__ mask8,
                                                const unsigned short* __restrict__ w2t,
                                                float* __restrict__ hidden,
                                                float* __restrict__ h2) {
  __shared__ __align__(16) char smem[32768];   // bf16 tile [32][512] / f32 partials [4][32][48]
  int w = threadIdx.x >> 6;
  int lane = threadIdx.x & 63;
  int m = lane & 15, kg = lane >> 4;
  int r0 = blockIdx.x * 32;                  // 32 rows per block
  int cw = w * 128;                          // 128 cols per wave
  f32x4 acc[2][8];
#pragma unroll
  for (int a = 0; a < 2; a++)
#pragma unroll
    for (int t = 0; t < 8; t++)
#pragma unroll
      for (int r = 0; r < 4; r++) acc[a][t][r] = 0.0f;

  const float* xa0 = axg + (size_t)(r0 + m) * FIN + kg * 8;
  const float* xa1 = xa0 + 16 * FIN;
#pragma unroll
  for (int kc = 0; kc < 4; kc++) {
    int kb = kc * 32;
    u32x4 a0l = *(const u32x4*)(xa0 + kb);
    u32x4 a0h = *(const u32x4*)(xa0 + kb + 4);
    u32x4 a1l = *(const u32x4*)(xa1 + kb);
    u32x4 a1h = *(const u32x4*)(xa1 + kb + 4);
    bf16x8 a0 = pack8t(a0l, a0h);
    bf16x8 a1 = pack8t(a1l, a1h);
#pragma unroll
    for (int t = 0; t < 8; t++) {
      const unsigned short* bp = w1t + (size_t)(cw + t * 16 + m) * FIN + kb + kg * 8;
      bf16x8 b = __builtin_bit_cast(bf16x8, *(const ushort8*)bp);
      // SWAPPED operand order: output fragment is H^T-laid-out
      acc[0][t] = __builtin_amdgcn_mfma_f32_16x16x32_bf16(b, a0, acc[0][t], 0, 0, 0);
      acc[1][t] = __builtin_amdgcn_mfma_f32_16x16x32_bf16(b, a1, acc[1][t], 0, 0, 0);
    }
  }

  // bias: 4 contiguous cols per (t): cw + t*16 + kg*4 + {0..3}
  f32x4 bq[8];
#pragma unroll
  for (int t = 0; t < 8; t++) bq[t] = *(const f32x4*)(b1 + cw + t * 16 + kg * 4);

  // mask: one 16 B segment per owned row (2 rows/lane), covering cols cw..cw+127
  u32x4 mv[2];
#pragma unroll
  for (int rt = 0; rt < 2; rt++)
    mv[rt] = *(const u32x4*)(mask8 + (size_t)(r0 + rt * 16 + m) * 64 + w * 16);

  // epilogue: float4 nontemporal hidden store + 8 B swizzled bf16 LDS stage
#pragma unroll
  for (int rt = 0; rt < 2; rt++) {
    int rowl = rt * 16 + m;                  // local row 0..31 (lane-owned)
    int sw = (rowl & 15) << 4;
#pragma unroll
    for (int t = 0; t < 8; t++) {
      f32x4 hv;
#pragma unroll
      for (int r = 0; r < 4; r++) {
        // bit index within u32 word (t>>1): (t&1)*16 + kg*4 + r
        float v = fmaxf(acc[rt][t][r] + bq[t][r], 0.0f);
        unsigned keep = (mv[rt][t >> 1] >> ((t & 1) * 16 + kg * 4 + r)) & 1u;
        hv[r] = keep ? v * 2.0f : 0.0f;
      }
      int colb = cw + t * 16 + kg * 4;       // 4 contiguous cols, 16 B aligned
      __builtin_nontemporal_store(__builtin_bit_cast(u32x4, hv),
          (u32x4*)(hidden + (size_t)(r0 + rowl) * FH + colb));
      // bf16 truncation (bit-identical to pack8t) into swizzled LDS tile
      unsigned lo = __builtin_amdgcn_perm(__float_as_uint(hv[1]), __float_as_uint(hv[0]), 0x07060302u);
      unsigned hi = __builtin_amdgcn_perm(__float_as_uint(hv[3]), __float_as_uint(hv[2]), 0x07060302u);
      uint2 p; p.x = lo; p.y = hi;
      *(uint2*)(smem + rowl * 1024 + ((colb * 2) ^ sw)) = p;
    }
  }
  __syncthreads();

  // phase 2: this wave contracts K slice [cw, cw+128) of the tile vs W2^T
  f32x4 acc2[2][3];
#pragma unroll
  for (int rt = 0; rt < 2; rt++)
#pragma unroll
    for (int t = 0; t < 3; t++)
#pragma unroll
      for (int r = 0; r < 4; r++) acc2[rt][t][r] = 0.0f;

#pragma unroll
  for (int kc = 0; kc < 4; kc++) {
    int colk = cw + kc * 32 + kg * 8;        // 8-col (16B) chunk, 16B-aligned
#pragma unroll
    for (int rt = 0; rt < 2; rt++) {
      int rowl = rt * 16 + m;                // A[m][k]: m = hidden row
      bf16x8 a = *(const bf16x8*)(smem + rowl * 1024 + ((colk * 2) ^ ((rowl & 15) << 4)));
#pragma unroll
      for (int t = 0; t < 3; t++) {
        bf16x8 b = __builtin_bit_cast(bf16x8,
            *(const ushort8*)(w2t + (size_t)(t * 16 + m) * FH + colk));
        acc2[rt][t] = __builtin_amdgcn_mfma_f32_16x16x32_bf16(a, b, acc2[rt][t], 0, 0, 0);
      }
    }
  }
  __syncthreads();                           // all tile reads done before overwrite

  // phase 3: cross-wave K-reduction via LDS partials [4][32][48]
  float* part = (float*)smem;
#pragma unroll
  for (int rt = 0; rt < 2; rt++)
#pragma unroll
    for (int t = 0; t < 3; t++)
#pragma unroll
      for (int r = 0; r < 4; r++) {
        int rowl = rt * 16 + kg * 4 + r;
        int coln = t * 16 + m;
        part[w * 1536 + rowl * 48 + coln] = acc2[rt][t][r];
      }
  __syncthreads();

  for (int idx = threadIdx.x; idx < 1536; idx += 256) {
    int rowl = idx / 48, coln = idx - rowl * 48;
    float s = part[idx] + part[1536 + idx] + part[3072 + idx] + part[4608 + idx];
    if (coln < FO) h2[(size_t)(r0 + rowl) * FO + coln] = s;
  }
}

// ---------------- aggregate L2 + bias -> out (f32) ----------------
// One THREAD per (node, channel); deg(i) independent 4 B gathers from the
// 16 MB L2/LLC-resident h2, latency hidden by TLP (4M threads).

__global__ __launch_bounds__(320) void k_agg2(const float* __restrict__ h2,
                                              const int* __restrict__ rowptr,
                                              const int* __restrict__ src_sorted,
                                              const float* __restrict__ dinv_src,
                                              const float* __restrict__ dinv,
                                              const float* __restrict__ b2,
                                              float* __restrict__ out) {
  int i = blockIdx.x * 8 + threadIdx.x / 40;   // node
  int ch = threadIdx.x % 40;                   // output channel
  int rs = rowptr[i], re = rowptr[i + 1];
  float di = dinv[i];
  float acc = 0.0f;

  int e = rs;
  for (; e + 2 <= re; e += 2) {                // 2 gathers in flight
    int s0 = src_sorted[e], s1 = src_sorted[e + 1];
    float w0 = dinv_src[e], w1_ = dinv_src[e + 1];
    float v0 = h2[(size_t)s0 * FO + ch];
    float v1 = h2[(size_t)s1 * FO + ch];
    acc += w0 * v0 + w1_ * v1;
  }
  if (e < re) {
    acc += dinv_src[e] * h2[(size_t)src_sorted[e] * FO + ch];
  }
  acc += di * h2[(size_t)i * FO + ch];         // self loop
  out[(size_t)i * FO + ch] = acc * di + b2[ch];
}

// ---------------- launcher ----------------

extern "C" void kernel_launch(void* const* d_in, const int* in_sizes, int n_in,
                              void* d_out, int out_size, void* d_ws, size_t ws_size,
                              hipStream_t stream) {
  const float* x  = (const float*)d_in[0];
  const int* ei   = (const int*)d_in[1];
  const float* w1 = (const float*)d_in[2];
  const float* b1 = (const float*)d_in[3];
  const float* w2 = (const float*)d_in[4];
  const float* b2 = (const float*)d_in[5];

  char* ws = (char*)d_ws;
  float* dinv            = (float*)(ws + O_DINV);
  int* cnt               = (int*)(ws + O_CNT);
  int* rowptr            = (int*)(ws + O_ROWPTR);
  int* cur               = (int*)(ws + O_CUR);
  int* src_sorted        = (int*)(ws + O_SRC);
  float* dinv_src        = (float*)(ws + O_DSRC);
  unsigned short* w1t    = (unsigned short*)(ws + O_W1T);
  unsigned short* w2t    = (unsigned short*)(ws + O_W2T);
  float* axg             = (float*)(ws + O_AXG);
  float* h2              = (float*)(ws + O_H2);
  unsigned char* mask8   = (unsigned char*)(ws + O_MASK);
  int* partials          = (int*)(ws + O_PART);

  float* outp   = (float*)d_out;                       // [N,40]
  float* hidden = outp + (size_t)N_NODES * FO;         // [N,512]

  const int* srcA = ei;             // edge_index[0]
  const int* dstA = ei + N_EDGES;   // edge_index[1]

  hipMemsetAsync(cnt, 0, N_NODES * sizeof(int), stream);
  k_count<<<(N_EDGES + 255) / 256, 256, 0, stream>>>(dstA, cnt);
  k_scan1tw<<<NCHUNK + TWBLKS, 256, 0, stream>>>(cnt, rowptr, partials, dinv,
                                                 w1, w2, w1t, w2t);
  k_scan3<<<NCHUNK, 256, 0, stream>>>(rowptr, partials, cur);
  k_scatter<<<(N_EDGES + 255) / 256, 256, 0, stream>>>(srcA, dstA, dinv, cur,
                                                       src_sorted, dinv_src);
  k_aggx<<<N_NODES / 4, 256, 0, stream>>>(x, rowptr, src_sorted, dinv_src, dinv,
                                          axg, mask8);
  k_gemm12<<<N_NODES / 32, 256, 0, stream>>>(axg, w1t, b1, mask8, w2t, hidden, h2);
  k_agg2<<<N_NODES / 8, 320, 0, stream>>>(h2, rowptr, src_sorted, dinv_src, dinv,
                                          b2, outp);
}